// Round 1
// baseline (220.692 us; speedup 1.0000x reference)
//
#include <hip/hip_runtime.h>

// Fused: per-channel affine+relu -> dilated 3x3 box-sum (zero pad) ->
// sigmoid gate -> multiply -> 2x nearest upsample -> add y.
// One thread handles 2 adjacent input pixels (w0, w0+1) and writes the
// corresponding 4-wide x 2-tall output block with float4 loads/stores.

#define DIA 2

__global__ __launch_bounds__(256) void shift_block_up_kernel(
    const float* __restrict__ x, const float* __restrict__ y,
    const float* __restrict__ w1v, const float* __restrict__ b1v,
    const float* __restrict__ w2v, const float* __restrict__ b2v,
    float* __restrict__ out)
{
    constexpr int C = 3, H = 512, W = 512;
    constexpr int W2 = 1024;

    int idx = blockIdx.x * blockDim.x + threadIdx.x;
    int wp = idx & (W / 2 - 1);          // 0..255  (pixel-pair index)
    int h  = (idx >> 8) & (H - 1);       // wave-uniform row
    int bc = idx >> 17;                  // 0..23  (b*C + c)
    int c  = bc % C;
    int w0 = wp * 2;

    const float s_w1 = w1v[c], s_b1 = b1v[c];
    const float s_w2 = w2v[c], s_b2 = b2v[c];

    const float* xp = x + (size_t)bc * (size_t)(H * W);

    float sum0 = 0.f, sum1 = 0.f;
    float xo0 = 0.f, xo1 = 0.f;

    #pragma unroll
    for (int i = 0; i < 3; ++i) {
        int hh = h + (i - 1) * DIA;
        bool hok = (unsigned)hh < (unsigned)H;
        const float* row = xp + (size_t)hh * W;
        #pragma unroll
        for (int j = 0; j < 3; ++j) {
            int wa = w0 + (j - 1) * DIA;     // tap for pixel 0
            int wb = wa + 1;                 // tap for pixel 1
            float va = (hok && (unsigned)wa < (unsigned)W)
                         ? fmaxf(row[wa] * s_w1 + s_b1, 0.f) : 0.f;
            float vb = (hok && (unsigned)wb < (unsigned)W)
                         ? fmaxf(row[wb] * s_w1 + s_b1, 0.f) : 0.f;
            sum0 += va;
            sum1 += vb;
            if (i == 1 && j == 1) { xo0 = va; xo1 = vb; }  // center = x_r
        }
    }

    float z0 = sum0 * s_w2 + s_b2;
    float z1 = sum1 * s_w2 + s_b2;
    float g0 = 1.f / (1.f + __expf(-z0));
    float g1 = 1.f / (1.f + __expf(-z1));
    float o0 = g0 * xo0;
    float o1 = g1 * xo1;

    // 2x nearest upsample + add y: 4 columns (2*w0 .. 2*w0+3), 2 rows.
    size_t obase = (size_t)bc * (size_t)(2 * H) * W2
                 + (size_t)(2 * h) * W2 + (size_t)(2 * w0);
    float4 ya = *(const float4*)(y + obase);
    float4 yb = *(const float4*)(y + obase + W2);
    *(float4*)(out + obase)      = make_float4(ya.x + o0, ya.y + o0, ya.z + o1, ya.w + o1);
    *(float4*)(out + obase + W2) = make_float4(yb.x + o0, yb.y + o0, yb.z + o1, yb.w + o1);
}

extern "C" void kernel_launch(void* const* d_in, const int* in_sizes, int n_in,
                              void* d_out, int out_size, void* d_ws, size_t ws_size,
                              hipStream_t stream) {
    const float* x  = (const float*)d_in[0];
    const float* y  = (const float*)d_in[1];
    const float* w1 = (const float*)d_in[2];
    const float* b1 = (const float*)d_in[3];
    const float* w2 = (const float*)d_in[4];
    const float* b2 = (const float*)d_in[5];
    float* out = (float*)d_out;

    constexpr int B = 8, C = 3, H = 512, W = 512;
    int total_threads = B * C * H * (W / 2);     // 3,145,728
    int block = 256;
    int grid = total_threads / block;            // 12,288
    shift_block_up_kernel<<<grid, block, 0, stream>>>(x, y, w1, b1, w2, b2, out);
}